// Round 1
// baseline (346.843 us; speedup 1.0000x reference)
//
#include <hip/hip_runtime.h>

// Problem constants (fixed by the reference):
#define E_ENV  8192
#define A_AG   128
#define K_PASS 512
#define ROW_F  11
#define SLICE_F  (K_PASS * ROW_F)   // 5632 floats per env slice (divisible by 4)
#define SLICE_V4 (SLICE_F / 4)      // 1408 float4 per env slice
#define ITERS    (SLICE_V4 / A_AG)  // 11 float4s per thread

// ---------------------------------------------------------------------------
// Single fused kernel: one block (128 threads, 2 waves) per env.
//  Phase 1: stage + resolve duplicate accepts (one pass of the reference
//           while_loop suffices: each iteration keeps only the env-argmin
//           among dup agents, which kills every other dup in one shot).
//  Phase 2: stream this env's contiguous 22.5 KB passenger slice from
//           `passengers` to `out` as float4s, patching columns 6/7/9/10
//           from the LDS overlay built in phase 1.
// All conflict state is env-local (targets are env-partitioned), so there
// are no cross-block races, and the full output write happens exactly once
// (no scattered read-modify-write stores into already-evicted lines).
// ---------------------------------------------------------------------------
__global__ __launch_bounds__(128) void k_fused(
    const float4* __restrict__ pass4,
    const int*    __restrict__ accepts,
    const int*    __restrict__ picks,
    const int*    __restrict__ targets,
    const float4* __restrict__ vectors,
    const int*    __restrict__ timesteps,
    float4*       __restrict__ out4)
{
    __shared__ int           cnt[K_PASS];      // dup counter per local passenger
    __shared__ int           agentOf[K_PASS];  // surviving accept agent, -1 none
    __shared__ unsigned char pickF[K_PASS];    // pick succeeded flag
    __shared__ float swv[2];
    __shared__ int   swi[2];

    const int e   = blockIdx.x;
    const int a   = threadIdx.x;            // agent 0..127
    const int gid = e * A_AG + a;

    // zero the per-env overlay
    #pragma unroll
    for (int j = 0; j < K_PASS / A_AG; ++j) {
        cnt[a + j * A_AG]     = 0;
        agentOf[a + j * A_AG] = -1;
        pickF[a + j * A_AG]   = 0;
    }
    __syncthreads();

    // ---- stage ----
    float4 v = vectors[gid];
    bool invalid = (v.x == -100.0f) && (v.y == -100.0f) &&
                   (v.z == -100.0f) && (v.w == -100.0f);
    float dx = v.x - v.z, dy = v.y - v.w;
    float d = sqrtf(dx * dx + dy * dy);
    if (invalid) d = INFINITY;

    const int  t    = targets[gid];          // global passenger id in [e*K,(e+1)*K)
    const int  tl   = t - e * K_PASS;        // local 0..511
    const bool acc  = accepts[gid] != 0;
    const bool pick = picks[gid] != 0;

    int at = acc ? t : -100;
    if (at >= 0) atomicAdd(&cnt[tl], 1);
    __syncthreads();

    // ---- resolve (single iteration of the reference while_loop) ----
    bool dup = (at >= 0) && (cnt[tl] > 1);
    float bv = dup ? d : INFINITY;
    int   bi = a;

    // wave-64 butterfly argmin, first-index tie-break
    #pragma unroll
    for (int off = 32; off > 0; off >>= 1) {
        float ov = __shfl_xor(bv, off);
        int   oi = __shfl_xor(bi, off);
        if (ov < bv || (ov == bv && oi < bi)) { bv = ov; bi = oi; }
    }
    int wave = a >> 6;
    if ((a & 63) == 0) { swv[wave] = bv; swi[wave] = bi; }
    __syncthreads();
    float v0 = swv[0], v1 = swv[1];
    int   i0 = swi[0], i1 = swi[1];
    // tie -> smaller index (wave 0) wins: matches jnp.argmin first-index
    int bidx = (v1 < v0 || (v1 == v0 && i1 < i0)) ? i1 : i0;

    int f = (dup && a != bidx) ? -100 : at;

    // build overlay: at most one surviving accept per passenger -> plain store
    if (f >= 0) agentOf[tl] = a;
    // multi-writers store the same value: benign
    if (pick && d < 1e-6f) pickF[tl] = 1;
    __syncthreads();

    const float tsf = (float)timesteps[e];

    // ---- copy + patch: stream the env slice once ----
    const float4* src = pass4 + (size_t)e * SLICE_V4;
    float4*       dst = out4  + (size_t)e * SLICE_V4;

    auto patch = [&](float val, unsigned row, int col) -> float {
        if (col == 6) {
            if (pickF[row]) return 2.0f;           // pick overrides accept
            if (agentOf[row] >= 0) return 1.0f;
        } else if (col == 7) {
            int ag = agentOf[row];
            if (ag >= 0) return (float)ag;
        } else if (col == 9) {
            if (agentOf[row] >= 0) return tsf;
        } else if (col == 10) {
            if (pickF[row]) return tsf;
        }
        return val;
    };

    int idx = a;                                  // float4 index within slice
    #pragma unroll
    for (int it = 0; it < ITERS; ++it, idx += A_AG) {
        float4 x = src[idx];
        unsigned g   = (unsigned)idx * 4u;        // element index 0..5631
        unsigned row = g / 11u;                   // magic-mul, cheap
        int      col = (int)(g - row * 11u);
        x.x = patch(x.x, row, col); if (++col == 11) { col = 0; ++row; }
        x.y = patch(x.y, row, col); if (++col == 11) { col = 0; ++row; }
        x.z = patch(x.z, row, col); if (++col == 11) { col = 0; ++row; }
        x.w = patch(x.w, row, col);
        dst[idx] = x;
    }
}

// ---------------------------------------------------------------------------
extern "C" void kernel_launch(void* const* d_in, const int* in_sizes, int n_in,
                              void* d_out, int out_size, void* d_ws, size_t ws_size,
                              hipStream_t stream)
{
    const float* passengers = (const float*)d_in[0];
    const int*   accepts    = (const int*)d_in[1];
    const int*   picks      = (const int*)d_in[2];
    const int*   targets    = (const int*)d_in[3];
    const float* vectors    = (const float*)d_in[4];
    const int*   timesteps  = (const int*)d_in[5];
    float*       out        = (float*)d_out;

    k_fused<<<E_ENV, A_AG, 0, stream>>>(
        (const float4*)passengers, accepts, picks, targets,
        (const float4*)vectors, timesteps, (float4*)out);
}